// Round 8
// baseline (318.230 us; speedup 1.0000x reference)
//
#include <hip/hip_runtime.h>

#define N_ 128
#define C_ 64
#define O_ 64
#define R_ 8
#define T_ 128
#define V_ 25
#define TV_ 3200   // T_*V_
#define EPS_ 1e-5f
#define G_ 8       // c-group per block in k5

// ---------------- kA: fused x3 + x1/x2 projections + V-pool, ONE pass over x ----
// grid (N_, 8): block y owns t in [16y, 16y+16). 256 threads, 200 active (g,v):
//   thread handles t = g + 16y + 8kk, kk in {0,1}, column v.
// Outputs: x3[n,r,t,v]; x12p[n,y,rr,v] (rr<8: w1-proj partial t-sum, rr>=8: w2);
//          ppool[n,r,t] = sum_v x3 (exact, block-exclusive t's, no global atomics).
__global__ __launch_bounds__(256) void kA(const float* __restrict__ x,
        const float* __restrict__ w5, const float* __restrict__ b5,
        const float* __restrict__ w1, const float* __restrict__ w2,
        float* __restrict__ x3, float* __restrict__ x12p, float* __restrict__ ppool) {
    int n = blockIdx.x, y = blockIdx.y;
    int tid = threadIdx.x;
    bool act = tid < 200;
    int g = tid / 25, v = tid % 25;
    __shared__ __align__(16) float wls[C_][24];   // [i][r'] r'<8:w5, 8..15:w1, 16..23:w2
    __shared__ float ppart[R_][16];
    __shared__ float s12part[16][25];
    for (int idx = tid; idx < C_ * 24; idx += 256) {
        int i = idx / 24, r = idx % 24;
        wls[i][r] = (r < 8) ? w5[r * C_ + i]
                  : (r < 16) ? w1[(r - 8) * C_ + i]
                             : w2[(r - 16) * C_ + i];
    }
    for (int idx = tid; idx < R_ * 16; idx += 256) (&ppart[0][0])[idx] = 0.f;
    for (int idx = tid; idx < 16 * 25; idx += 256) (&s12part[0][0])[idx] = 0.f;
    __syncthreads();

    float acc0[R_], acc1[R_], s12[16];
    #pragma unroll
    for (int r = 0; r < R_; ++r) { acc0[r] = 0.f; acc1[r] = 0.f; }
    #pragma unroll
    for (int rr = 0; rr < 16; ++rr) s12[rr] = 0.f;

    if (act) {
        int off0 = (g + 16 * y) * 25 + v;       // t for kk=0
        const float* xp = x + (size_t)n * C_ * TV_;
        #pragma unroll 2
        for (int i = 0; i < C_; ++i) {
            float xv0 = xp[(size_t)i * TV_ + off0];
            float xv1 = xp[(size_t)i * TV_ + off0 + 200];
            const float4* wp = (const float4*)&wls[i][0];
            float4 q0 = wp[0], q1 = wp[1];      // w5 rows 0..7
            float4 q2 = wp[2], q3 = wp[3];      // w1 rows 0..7
            float4 q4 = wp[4], q5 = wp[5];      // w2 rows 0..7
            acc0[0] += q0.x * xv0; acc0[1] += q0.y * xv0; acc0[2] += q0.z * xv0; acc0[3] += q0.w * xv0;
            acc0[4] += q1.x * xv0; acc0[5] += q1.y * xv0; acc0[6] += q1.z * xv0; acc0[7] += q1.w * xv0;
            acc1[0] += q0.x * xv1; acc1[1] += q0.y * xv1; acc1[2] += q0.z * xv1; acc1[3] += q0.w * xv1;
            acc1[4] += q1.x * xv1; acc1[5] += q1.y * xv1; acc1[6] += q1.z * xv1; acc1[7] += q1.w * xv1;
            float xs = xv0 + xv1;               // same v, both t's: projections sum over t
            s12[0]  += q2.x * xs; s12[1]  += q2.y * xs; s12[2]  += q2.z * xs; s12[3]  += q2.w * xs;
            s12[4]  += q3.x * xs; s12[5]  += q3.y * xs; s12[6]  += q3.z * xs; s12[7]  += q3.w * xs;
            s12[8]  += q4.x * xs; s12[9]  += q4.y * xs; s12[10] += q4.z * xs; s12[11] += q4.w * xs;
            s12[12] += q5.x * xs; s12[13] += q5.y * xs; s12[14] += q5.z * xs; s12[15] += q5.w * xs;
        }
        // x3 write + ppool partial (end-of-block atomics only)
        float* x3p = x3 + (size_t)n * R_ * TV_;
        #pragma unroll
        for (int r = 0; r < R_; ++r) {
            float v0 = acc0[r] + b5[r];
            float v1 = acc1[r] + b5[r];
            x3p[(size_t)r * TV_ + off0]       = v0;
            x3p[(size_t)r * TV_ + off0 + 200] = v1;
            atomicAdd(&ppart[r][g], v0);
            atomicAdd(&ppart[r][g + 8], v1);
        }
        #pragma unroll
        for (int rr = 0; rr < 16; ++rr) atomicAdd(&s12part[rr][v], s12[rr]);
    }
    __syncthreads();
    if (tid < 128) {
        int r = tid / 16, tl = tid % 16;        // tl = g + 8kk  -> t = 16y + tl? No:
        // t = g + 16y + 8kk; tl index in ppart is g (kk=0) or g+8 (kk=1)
        // so t = 16y + (tl%8) + 8*(tl/8)  ... careful: ppart[r][g]=t(16y+g), ppart[r][g+8]=t(16y+g+8)
        ppool[((size_t)n * R_ + r) * T_ + 16 * y + tl] = ppart[r][tl];
    }
    for (int idx = tid; idx < 400; idx += 256)
        x12p[((size_t)n * 8 + y) * 400 + idx] = (&s12part[0][0])[idx];
}

// ---------------- kB: rel2 (y<4) + RouteFuncMLP (y==4), grid (N_, 5) ----------------
__global__ __launch_bounds__(256) void kB(const float* __restrict__ x12p,
        const float* __restrict__ b1, const float* __restrict__ b2,
        const float* __restrict__ w4, const float* __restrict__ b4,
        const float* __restrict__ A, const float* __restrict__ alpha,
        const float* __restrict__ ppool,
        const float* __restrict__ g_w, const float* __restrict__ g_b,
        const float* __restrict__ a_w, const float* __restrict__ a_b,
        const float* __restrict__ bn_g, const float* __restrict__ bn_b,
        const float* __restrict__ bn_rm, const float* __restrict__ bn_rv,
        const float* __restrict__ rf_bw,
        float* __restrict__ rel2, float* __restrict__ rf) {
    int n = blockIdx.x, tid = threadIdx.x;
    if (blockIdx.y == 4) {
        // ---- RouteFuncMLP, full T in one block ----
        __shared__ float ps[R_][T_];
        __shared__ float hsx[R_][T_ + 2];      // zero-padded h: h(t) at hsx[r][t+1]
        __shared__ float gs[R_], ggs[R_];
        for (int idx = tid; idx < R_ * T_; idx += 256)
            ps[idx / T_][idx % T_] = ppool[(size_t)n * R_ * T_ + idx] * (1.0f / V_);
        if (tid < R_ * 2) {                     // zero both pad columns
            int r = tid / 2;
            hsx[r][(tid % 2) * (T_ + 1)] = 0.f;
        }
        __syncthreads();
        if (tid < R_) {
            float s = 0.f;
            for (int t = 0; t < T_; ++t) s += ps[tid][t];
            gs[tid] = s * (1.0f / T_);
        }
        __syncthreads();
        if (tid < R_) {
            float a = g_b[tid];
            #pragma unroll
            for (int i = 0; i < R_; ++i) a += g_w[tid * R_ + i] * gs[i];
            ggs[tid] = a;
        }
        __syncthreads();
        for (int idx = tid; idx < R_ * T_; idx += 256) {
            int r = idx / T_, t = idx % T_;
            float acc = a_b[r];
            #pragma unroll
            for (int i = 0; i < R_; ++i) {
                #pragma unroll
                for (int k = 0; k < 3; ++k) {
                    int tt = t + k - 1;
                    if (tt >= 0 && tt < T_)
                        acc += a_w[(r * R_ + i) * 3 + k] * (ps[i][tt] + ggs[i]);
                }
            }
            float sc = bn_g[r] * rsqrtf(bn_rv[r] + EPS_);
            hsx[r][t + 1] = fmaxf((acc - bn_rm[r]) * sc + bn_b[r], 0.f);
        }
        __syncthreads();
        for (int idx = tid; idx < R_ * T_; idx += 256) {
            int r = idx / T_, t = idx % T_;
            float acc = 1.0f;
            #pragma unroll
            for (int i = 0; i < R_; ++i) {
                #pragma unroll
                for (int k = 0; k < 3; ++k)
                    acc += rf_bw[(r * R_ + i) * 3 + k] * hsx[i][t + k];
            }
            rf[((size_t)n * R_ + r) * T_ + t] = acc;
        }
        return;
    }
    // ---- rel2, 16 output channels per block ----
    int c0 = blockIdx.y * 16;
    __shared__ float x1s[R_ * V_];
    __shared__ float x2s[R_ * V_];
    __shared__ float rels[R_ * 625];
    const float invT = 1.0f / (float)T_;
    for (int idx = tid; idx < 400; idx += 256) {
        int rr = idx / 25;
        float a = 0.f;
        #pragma unroll
        for (int b = 0; b < 8; ++b) a += x12p[((size_t)n * 8 + b) * 400 + idx];
        a = a * invT + ((rr < 8) ? b1[rr] : b2[rr - 8]);
        if (rr < 8) x1s[idx] = a; else x2s[idx - 200] = a;
    }
    __syncthreads();
    for (int idx = tid; idx < R_ * 625; idx += 256) {
        int r = idx / 625, uv = idx % 625;
        rels[idx] = tanhf(x1s[r * V_ + uv / V_] - x2s[r * V_ + uv % V_]);
    }
    __syncthreads();
    float al = alpha[0];
    for (int idx = tid; idx < 16 * 625; idx += 256) {
        int o = c0 + idx / 625, uv = idx % 625;
        float acc = b4[o];
        #pragma unroll
        for (int r = 0; r < R_; ++r) acc += w4[o * R_ + r] * rels[r * 625 + uv];
        rel2[((size_t)n * O_ + o) * 625 + uv] = acc * al + A[uv];
    }
}

// ---------------- K5: out[n,c,t,u] = sum_v rel2[n,c,u,v] * z[n,c,t,v] ----------------
// grid 2048, block 512; XCD-swizzled so all 16 blocks of one n share an XCD's L2.
__global__ __launch_bounds__(512) void k5_out(const float* __restrict__ x3,
        const float* __restrict__ rf, const float* __restrict__ rel2,
        const float* __restrict__ w3, const float* __restrict__ b3,
        float* __restrict__ out) {
    int b = blockIdx.x;
    int xcd = b & 7, slot = b >> 3;
    int n = (slot >> 4) * 8 + xcd;             // all 16 blocks of n on one XCD
    int rem = slot & 15;
    int cg = rem >> 1, th = rem & 1;
    int c0 = cg * G_;
    int tid = threadIdx.x;
    __shared__ float rfs[R_][64];              // 2 KB
    __shared__ __align__(16) float zs[G_][1600];  // 51.2 KB
    {
        int r = tid / 64, tl = tid % 64;
        rfs[r][tl] = rf[((size_t)n * R_ + r) * T_ + th * 64 + tl];
    }
    __syncthreads();
    const float* x3p = x3 + (size_t)n * R_ * TV_ + th * 1600;
    for (int p = tid; p < 1600; p += 512) {
        int t = p / V_;
        float y[R_];
        #pragma unroll
        for (int r = 0; r < R_; ++r) y[r] = x3p[(size_t)r * TV_ + p] * rfs[r][t];
        #pragma unroll
        for (int cl = 0; cl < G_; ++cl) {
            float a = b3[c0 + cl];
            #pragma unroll
            for (int r = 0; r < R_; ++r) a += w3[(c0 + cl) * R_ + r] * y[r];
            zs[cl][p] = a;
        }
    }
    __syncthreads();
    {
        int cl = __builtin_amdgcn_readfirstlane(tid >> 6);
        int tl = tid & 63;
        const float* relp = rel2 + ((size_t)n * O_ + c0 + cl) * 625;
        float zreg[V_];
        #pragma unroll
        for (int v = 0; v < V_; ++v) zreg[v] = zs[cl][tl * V_ + v];
        float accu[V_];
        #pragma unroll
        for (int u = 0; u < V_; ++u) {
            float acc = 0.f;
            #pragma unroll
            for (int j = 0; j < V_; ++j) acc += relp[u * V_ + j] * zreg[j];
            accu[u] = acc;
        }
        #pragma unroll
        for (int u = 0; u < V_; ++u) zs[cl][tl * V_ + u] = accu[u];
    }
    __syncthreads();
    size_t ob = (((size_t)n * O_ + c0) * T_ + th * 64) * V_;
    float4* out4 = (float4*)(out + ob);
    const float4* zf4 = (const float4*)&zs[0][0];
    for (int j = tid; j < 3200; j += 512) {
        int cl = j / 400, r4 = j % 400;
        out4[(size_t)cl * 800 + r4] = zf4[j];
    }
}

extern "C" void kernel_launch(void* const* d_in, const int* in_sizes, int n_in,
                              void* d_out, int out_size, void* d_ws, size_t ws_size,
                              hipStream_t stream) {
    const float* x     = (const float*)d_in[0];
    const float* A     = (const float*)d_in[1];
    const float* alpha = (const float*)d_in[2];
    const float* w1    = (const float*)d_in[3];
    const float* b1    = (const float*)d_in[4];
    const float* w2    = (const float*)d_in[5];
    const float* b2    = (const float*)d_in[6];
    const float* w5    = (const float*)d_in[7];
    const float* b5    = (const float*)d_in[8];
    const float* w3    = (const float*)d_in[9];
    const float* b3    = (const float*)d_in[10];
    const float* w4    = (const float*)d_in[11];
    const float* b4    = (const float*)d_in[12];
    const float* g_w   = (const float*)d_in[13];
    const float* g_b   = (const float*)d_in[14];
    const float* a_w   = (const float*)d_in[15];
    const float* a_b   = (const float*)d_in[16];
    const float* bn_g  = (const float*)d_in[17];
    const float* bn_b  = (const float*)d_in[18];
    const float* bn_rm = (const float*)d_in[19];
    const float* bn_rv = (const float*)d_in[20];
    const float* rf_bw = (const float*)d_in[21];
    float* out = (float*)d_out;
    float* ws  = (float*)d_ws;

    float* x3    = ws;                          // 3,276,800
    float* x12p  = x3 + 3276800;                // 409,600 (=128*8*400)
    float* ppool = x12p + 409600;               // 131,072
    float* rf    = ppool + 131072;              // 131,072
    float* rel2  = rf + 131072;                 // 5,120,000

    hipLaunchKernelGGL(kA, dim3(N_, 8), dim3(256), 0, stream,
                       x, w5, b5, w1, w2, x3, x12p, ppool);
    hipLaunchKernelGGL(kB, dim3(N_, 5), dim3(256), 0, stream,
                       x12p, b1, b2, w4, b4, A, alpha,
                       ppool, g_w, g_b, a_w, a_b, bn_g, bn_b, bn_rm, bn_rv, rf_bw,
                       rel2, rf);
    hipLaunchKernelGGL(k5_out, dim3(N_ * 16), dim3(512), 0, stream,
                       x3, rf, rel2, w3, b3, out);
}

// Round 10
// 306.340 us; speedup vs baseline: 1.0388x; 1.0388x over previous
//
#include <hip/hip_runtime.h>

#define N_ 128
#define C_ 64
#define O_ 64
#define R_ 8
#define T_ 128
#define V_ 25
#define TV_ 3200   // T_*V_
#define EPS_ 1e-5f
#define G_ 8       // c-group per block in k5

// ---------------- kA: fused x3 + x1/x2 projections + V-pool, ONE pass over x ----
// grid (N_, 16): block y owns t in [8y, 8y+8). 256 threads, 200 active (g,v):
//   thread handles t = 8y+g, column v. 64-deep i-loop, unroll 4, weights via
//   wave-uniform scalar loads. No atomics: LDS stores + tree reductions.
__global__ __launch_bounds__(256) void kA(const float* __restrict__ x,
        const float* __restrict__ w5, const float* __restrict__ b5,
        const float* __restrict__ w1, const float* __restrict__ w2,
        float* __restrict__ x3, float* __restrict__ x12p, float* __restrict__ ppool) {
    int n = blockIdx.x, y = blockIdx.y;
    int tid = threadIdx.x;
    int g = tid / 25, v = tid % 25;
    bool act = tid < 200;
    __shared__ float x3buf[R_][8][25];         // 6.4 KB: x3 values for ppool reduce
    __shared__ float s12full[8][16 * 25];      // 12.8 KB: per-g projection partials

    float acc[R_], s12[16];
    #pragma unroll
    for (int r = 0; r < R_; ++r) acc[r] = 0.f;
    #pragma unroll
    for (int rr = 0; rr < 16; ++rr) s12[rr] = 0.f;

    if (act) {
        int off = (8 * y + g) * 25 + v;
        const float* xp = x + (size_t)n * C_ * TV_ + off;
        #pragma unroll 4
        for (int i = 0; i < C_; ++i) {
            float xv = xp[(size_t)i * TV_];
            #pragma unroll
            for (int r = 0; r < R_; ++r) acc[r]     += w5[r * C_ + i] * xv;
            #pragma unroll
            for (int r = 0; r < R_; ++r) s12[r]     += w1[r * C_ + i] * xv;
            #pragma unroll
            for (int r = 0; r < R_; ++r) s12[r + 8] += w2[r * C_ + i] * xv;
        }
        float* x3p = x3 + (size_t)n * R_ * TV_ + (8 * y + g) * 25 + v;
        #pragma unroll
        for (int r = 0; r < R_; ++r) {
            float val = acc[r] + b5[r];
            x3p[(size_t)r * TV_] = val;
            x3buf[r][g][v] = val;
        }
        #pragma unroll
        for (int rr = 0; rr < 16; ++rr) s12full[g][rr * 25 + v] = s12[rr];
    }
    __syncthreads();
    // ppool[n,r,t] = sum_v x3 (raw sum; kB scales by 1/V)
    if (tid < 64) {
        int r = tid / 8, tl = tid % 8;
        float s = 0.f;
        #pragma unroll
        for (int vv = 0; vv < V_; ++vv) s += x3buf[r][tl][vv];
        ppool[((size_t)n * R_ + r) * T_ + 8 * y + tl] = s;
    }
    // x12p[n,y,rr*25+v] = sum_g s12full
    for (int idx = tid; idx < 400; idx += 256) {
        float s = 0.f;
        #pragma unroll
        for (int gg = 0; gg < 8; ++gg) s += s12full[gg][idx];
        x12p[((size_t)n * 16 + y) * 400 + idx] = s;
    }
}

// ---------------- kB: rel2 (y<4) + RouteFuncMLP (y==4), grid (N_, 5) ----------------
__global__ __launch_bounds__(256) void kB(const float* __restrict__ x12p,
        const float* __restrict__ b1, const float* __restrict__ b2,
        const float* __restrict__ w4, const float* __restrict__ b4,
        const float* __restrict__ A, const float* __restrict__ alpha,
        const float* __restrict__ ppool,
        const float* __restrict__ g_w, const float* __restrict__ g_b,
        const float* __restrict__ a_w, const float* __restrict__ a_b,
        const float* __restrict__ bn_g, const float* __restrict__ bn_b,
        const float* __restrict__ bn_rm, const float* __restrict__ bn_rv,
        const float* __restrict__ rf_bw,
        float* __restrict__ rel2, float* __restrict__ rf) {
    int n = blockIdx.x, tid = threadIdx.x;
    if (blockIdx.y == 4) {
        // ---- RouteFuncMLP, full T in one block ----
        __shared__ float ps[R_][T_];
        __shared__ float hsx[R_][T_ + 2];      // zero-padded h: h(t) at hsx[r][t+1]
        __shared__ float gs[R_], ggs[R_];
        for (int idx = tid; idx < R_ * T_; idx += 256)
            ps[idx / T_][idx % T_] = ppool[(size_t)n * R_ * T_ + idx] * (1.0f / V_);
        if (tid < R_ * 2) {                     // zero both pad columns
            int r = tid / 2;
            hsx[r][(tid % 2) * (T_ + 1)] = 0.f;
        }
        __syncthreads();
        if (tid < R_) {
            float s = 0.f;
            for (int t = 0; t < T_; ++t) s += ps[tid][t];
            gs[tid] = s * (1.0f / T_);
        }
        __syncthreads();
        if (tid < R_) {
            float a = g_b[tid];
            #pragma unroll
            for (int i = 0; i < R_; ++i) a += g_w[tid * R_ + i] * gs[i];
            ggs[tid] = a;
        }
        __syncthreads();
        for (int idx = tid; idx < R_ * T_; idx += 256) {
            int r = idx / T_, t = idx % T_;
            float acc = a_b[r];
            #pragma unroll
            for (int i = 0; i < R_; ++i) {
                #pragma unroll
                for (int k = 0; k < 3; ++k) {
                    int tt = t + k - 1;
                    if (tt >= 0 && tt < T_)
                        acc += a_w[(r * R_ + i) * 3 + k] * (ps[i][tt] + ggs[i]);
                }
            }
            float sc = bn_g[r] * rsqrtf(bn_rv[r] + EPS_);
            hsx[r][t + 1] = fmaxf((acc - bn_rm[r]) * sc + bn_b[r], 0.f);
        }
        __syncthreads();
        for (int idx = tid; idx < R_ * T_; idx += 256) {
            int r = idx / T_, t = idx % T_;
            float acc = 1.0f;
            #pragma unroll
            for (int i = 0; i < R_; ++i) {
                #pragma unroll
                for (int k = 0; k < 3; ++k)
                    acc += rf_bw[(r * R_ + i) * 3 + k] * hsx[i][t + k];
            }
            rf[((size_t)n * R_ + r) * T_ + t] = acc;
        }
        return;
    }
    // ---- rel2, 16 output channels per block ----
    int c0 = blockIdx.y * 16;
    __shared__ float x1s[R_ * V_];
    __shared__ float x2s[R_ * V_];
    __shared__ float rels[R_ * 625];
    const float invT = 1.0f / (float)T_;
    for (int idx = tid; idx < 400; idx += 256) {
        int rr = idx / 25;
        float a = 0.f;
        #pragma unroll
        for (int b = 0; b < 16; ++b) a += x12p[((size_t)n * 16 + b) * 400 + idx];
        a = a * invT + ((rr < 8) ? b1[rr] : b2[rr - 8]);
        if (rr < 8) x1s[idx] = a; else x2s[idx - 200] = a;
    }
    __syncthreads();
    for (int idx = tid; idx < R_ * 625; idx += 256) {
        int r = idx / 625, uv = idx % 625;
        rels[idx] = tanhf(x1s[r * V_ + uv / V_] - x2s[r * V_ + uv % V_]);
    }
    __syncthreads();
    float al = alpha[0];
    for (int idx = tid; idx < 16 * 625; idx += 256) {
        int o = c0 + idx / 625, uv = idx % 625;
        float acc = b4[o];
        #pragma unroll
        for (int r = 0; r < R_; ++r) acc += w4[o * R_ + r] * rels[r * 625 + uv];
        rel2[((size_t)n * O_ + o) * 625 + uv] = acc * al + A[uv];
    }
}

// ---------------- K5: out[n,c,t,u] = sum_v rel2[n,c,u,v] * z[n,c,t,v] ----------------
// grid N*8*2 (c-group of 8, t-half), block 512 (8 waves; wave = one channel).
// rel read via wave-uniform scalar loads (s_load), not LDS. (No XCD swizzle.)
__global__ __launch_bounds__(512) void k5_out(const float* __restrict__ x3,
        const float* __restrict__ rf, const float* __restrict__ rel2,
        const float* __restrict__ w3, const float* __restrict__ b3,
        float* __restrict__ out) {
    int b = blockIdx.x;
    int n = b / 16;
    int rem = b % 16;
    int cg = rem / 2, th = rem % 2;
    int c0 = cg * G_;
    int tid = threadIdx.x;
    __shared__ float rfs[R_][64];              // 2 KB
    __shared__ __align__(16) float zs[G_][1600];  // 51.2 KB
    {
        int r = tid / 64, tl = tid % 64;
        rfs[r][tl] = rf[((size_t)n * R_ + r) * T_ + th * 64 + tl];
    }
    __syncthreads();
    const float* x3p = x3 + (size_t)n * R_ * TV_ + th * 1600;
    for (int p = tid; p < 1600; p += 512) {
        int t = p / V_;
        float y[R_];
        #pragma unroll
        for (int r = 0; r < R_; ++r) y[r] = x3p[(size_t)r * TV_ + p] * rfs[r][t];
        #pragma unroll
        for (int cl = 0; cl < G_; ++cl) {
            float a = b3[c0 + cl];
            #pragma unroll
            for (int r = 0; r < R_; ++r) a += w3[(c0 + cl) * R_ + r] * y[r];
            zs[cl][p] = a;
        }
    }
    __syncthreads();
    {
        int cl = __builtin_amdgcn_readfirstlane(tid >> 6);
        int tl = tid & 63;
        const float* relp = rel2 + ((size_t)n * O_ + c0 + cl) * 625;
        float zreg[V_];
        #pragma unroll
        for (int v = 0; v < V_; ++v) zreg[v] = zs[cl][tl * V_ + v];
        float accu[V_];
        #pragma unroll
        for (int u = 0; u < V_; ++u) {
            float acc = 0.f;
            #pragma unroll
            for (int j = 0; j < V_; ++j) acc += relp[u * V_ + j] * zreg[j];
            accu[u] = acc;
        }
        #pragma unroll
        for (int u = 0; u < V_; ++u) zs[cl][tl * V_ + u] = accu[u];
    }
    __syncthreads();
    size_t ob = (((size_t)n * O_ + c0) * T_ + th * 64) * V_;
    float4* out4 = (float4*)(out + ob);
    const float4* zf4 = (const float4*)&zs[0][0];
    for (int j = tid; j < 3200; j += 512) {
        int cl = j / 400, r4 = j % 400;
        out4[(size_t)cl * 800 + r4] = zf4[j];
    }
}

extern "C" void kernel_launch(void* const* d_in, const int* in_sizes, int n_in,
                              void* d_out, int out_size, void* d_ws, size_t ws_size,
                              hipStream_t stream) {
    const float* x     = (const float*)d_in[0];
    const float* A     = (const float*)d_in[1];
    const float* alpha = (const float*)d_in[2];
    const float* w1    = (const float*)d_in[3];
    const float* b1    = (const float*)d_in[4];
    const float* w2    = (const float*)d_in[5];
    const float* b2    = (const float*)d_in[6];
    const float* w5    = (const float*)d_in[7];
    const float* b5    = (const float*)d_in[8];
    const float* w3    = (const float*)d_in[9];
    const float* b3    = (const float*)d_in[10];
    const float* w4    = (const float*)d_in[11];
    const float* b4    = (const float*)d_in[12];
    const float* g_w   = (const float*)d_in[13];
    const float* g_b   = (const float*)d_in[14];
    const float* a_w   = (const float*)d_in[15];
    const float* a_b   = (const float*)d_in[16];
    const float* bn_g  = (const float*)d_in[17];
    const float* bn_b  = (const float*)d_in[18];
    const float* bn_rm = (const float*)d_in[19];
    const float* bn_rv = (const float*)d_in[20];
    const float* rf_bw = (const float*)d_in[21];
    float* out = (float*)d_out;
    float* ws  = (float*)d_ws;

    float* x3    = ws;                          // 3,276,800
    float* x12p  = x3 + 3276800;                // 819,200 (=128*16*400)
    float* ppool = x12p + 819200;               // 131,072
    float* rf    = ppool + 131072;              // 131,072
    float* rel2  = rf + 131072;                 // 5,120,000

    hipLaunchKernelGGL(kA, dim3(N_, 16), dim3(256), 0, stream,
                       x, w5, b5, w1, w2, x3, x12p, ppool);
    hipLaunchKernelGGL(kB, dim3(N_, 5), dim3(256), 0, stream,
                       x12p, b1, b2, w4, b4, A, alpha,
                       ppool, g_w, g_b, a_w, a_b, bn_g, bn_b, bn_rm, bn_rv, rf_bw,
                       rel2, rf);
    hipLaunchKernelGGL(k5_out, dim3(N_ * 16), dim3(512), 0, stream,
                       x3, rf, rel2, w3, b3, out);
}